// Round 5
// baseline (2092.503 us; speedup 1.0000x reference)
//
#include <hip/hip_runtime.h>

// AnchorStore: KL-argmin 1-NN.
//   score[b,k] = sum_d A[k,d]*log A[k,d]  -  sum_d A[k,d]*log Q[b,d]
//   out[b] = label[argmin_k score[b,k]],  K=2048, D=50257, B=256.
// bf16 MFMA GEMM (approx cross) with deterministic per-D-chunk partials in ws
// (no lq buffer -> partials fit the ~26-30MB workspace), on-the-fly log(Q),
// double-buffered LDS with 1 barrier/step (full-step prefetch), exact fp32
// self-term, gap-gated fp64 top-8 rescore, label gather.

constexpr int K   = 2048;
constexpr int D   = 50257;
constexpr int B   = 256;
constexpr int BM  = 64;
constexpr int BK  = 64;
constexpr int NC  = 8;
constexpr float MARGIN = 4.0f;   // approx-score gap below which we rescore

typedef __attribute__((ext_vector_type(8))) short bf16x8;
typedef __attribute__((ext_vector_type(4))) float f32x4;
typedef __attribute__((ext_vector_type(8))) unsigned short u16x8;

__device__ inline unsigned short f2bf_rne(float f) {
    union { float f; unsigned u; } v; v.f = f;
    unsigned r = v.u + 0x7FFFu + ((v.u >> 16) & 1u);
    return (unsigned short)(r >> 16);
}

// ---------------- main GEMM: cross[b][k] partials over D-chunks ----------------
// WSP: deterministic part[z][B][K] stores; else atomicAdd into cross[B][K].
template<bool WSP>
__global__ __launch_bounds__(512, 4)
void gemm_kernel(const float* __restrict__ anchor,
                 const float* __restrict__ query,
                 float* __restrict__ outc,
                 float* __restrict__ selfp,   // [sch][K]
                 int dc, int sch)
{
    // XCD-grouped swizzle: consecutive g on one XCD; all 32 x-blocks of a z
    // land on 1-2 XCDs so the Q slice stays L2-resident.
    const int nb8 = gridDim.x >> 3;                      // blocks per XCD
    const int g   = (blockIdx.x & 7) * nb8 + (blockIdx.x >> 3);
    const int z   = g >> 5;
    const int x   = g & 31;

    const int t    = threadIdx.x;
    const int k0   = x * BM;
    const int d0   = z * dc;
    const int dend = min(d0 + dc, D);

    // double-buffered LDS: A rows [0,64), Q rows [64,320), 64 ushorts/row
    __shared__ __align__(16) unsigned short lds[2][(BM + B) * 64];  // 2 x 40 KB

    // A staging: row = t>>3 (0..63), 8 cols at (t&7)*8
    const int rowA = t >> 3;
    const int tq8  = t & 7;
    const int ar   = k0 + rowA;
    const int swA  = (rowA & 7) << 3;
    const float* Arow = anchor + (size_t)ar * D;

    // Q staging: row = t>>1 (0..255), 32 cols at (t&1)*32
    const int rowQ = t >> 1;
    const int hq   = t & 1;
    const int swQ  = (rowQ & 7) << 3;
    const float* Qrow = query + (size_t)rowQ * D;

    // MFMA geometry: 8 waves in 2(m) x 4(n); wave tile 32x64
    const int w    = t >> 6;
    const int lane = t & 63;
    const int wm   = (w >> 2) * 32;
    const int wn   = (w & 3) * 64;
    const int lrow = lane & 15;
    const int kg   = lane >> 4;

    f32x4 acc[2][4];
#pragma unroll
    for (int mt = 0; mt < 2; ++mt)
#pragma unroll
        for (int nt = 0; nt < 4; ++nt)
#pragma unroll
            for (int i = 0; i < 4; ++i) acc[mt][nt][i] = 0.f;

    float selfacc = 0.f;

    float wfA[12]; int phA = 0;
    float wfQ[36]; int phQ = 0;

    auto load_step = [&](int dt) {
        // ---- A: 8 wanted cols; 3 aligned float4 cover [g0-ph, g0-ph+12) ----
        const int dbase = dt + tq8 * 8;
        if (dbase + 12 <= dend) {
            const size_t g0 = (size_t)ar * D + dbase;
            phA = (int)(g0 & 3);
            const float4* wp = reinterpret_cast<const float4*>(anchor + (g0 - phA));
            const float4 w0 = wp[0], w1 = wp[1], w2 = wp[2];
            wfA[0] = w0.x; wfA[1]  = w0.y; wfA[2]  = w0.z; wfA[3]  = w0.w;
            wfA[4] = w1.x; wfA[5]  = w1.y; wfA[6]  = w1.z; wfA[7]  = w1.w;
            wfA[8] = w2.x; wfA[9]  = w2.y; wfA[10] = w2.z; wfA[11] = w2.w;
        } else {
            phA = 0;
#pragma unroll
            for (int j = 0; j < 8; ++j) {
                const int d = dbase + j;
                wfA[j] = (d < dend) ? Arow[d] : 0.f;
            }
#pragma unroll
            for (int j = 8; j < 12; ++j) wfA[j] = 0.f;
        }
        // ---- Q: 32 wanted cols; 9 aligned float4 cover [g0-ph, g0-ph+36) ----
        const int qb = dt + hq * 32;
        if (qb + 36 <= dend) {
            const size_t g0 = (size_t)rowQ * D + qb;
            phQ = (int)(g0 & 3);
            const float4* wp = reinterpret_cast<const float4*>(query + (g0 - phQ));
#pragma unroll
            for (int gg = 0; gg < 9; ++gg) {
                const float4 v = wp[gg];
                wfQ[gg * 4 + 0] = v.x; wfQ[gg * 4 + 1] = v.y;
                wfQ[gg * 4 + 2] = v.z; wfQ[gg * 4 + 3] = v.w;
            }
        } else {
            phQ = 0;
#pragma unroll
            for (int j = 0; j < 32; ++j) {
                const int d = qb + j;
                wfQ[j] = (d < dend) ? Qrow[d] : 1.f;   // log(1)=0
            }
#pragma unroll
            for (int j = 32; j < 36; ++j) wfQ[j] = 1.f;
        }
    };

    auto convert_write = [&](int p) {
        // ---- A: phase-select 8, fused exact self-term, bf16, store ----
        float sA[9], av[8];
#pragma unroll
        for (int j = 0; j < 9; ++j) sA[j] = (phA & 2) ? wfA[j + 2] : wfA[j];
#pragma unroll
        for (int j = 0; j < 8; ++j) av[j] = (phA & 1) ? sA[j + 1] : sA[j];
        unsigned short abf[8];
#pragma unroll
        for (int j = 0; j < 8; ++j) {
            if (av[j] > 0.f) selfacc = fmaf(av[j], __logf(av[j]), selfacc);
            abf[j] = f2bf_rne(av[j]);
        }
        unsigned short* a0 = &lds[p][rowA * 64 + ((tq8 * 8) ^ swA)];
        reinterpret_cast<ushort4*>(a0)[0] = ushort4{abf[0], abf[1], abf[2], abf[3]};
        reinterpret_cast<ushort4*>(a0)[1] = ushort4{abf[4], abf[5], abf[6], abf[7]};
        // ---- Q: phase-select 32, log, bf16, store ----
        float sQ[34], qv[32];
#pragma unroll
        for (int j = 0; j < 34; ++j) sQ[j] = (phQ & 2) ? wfQ[j + 2] : wfQ[j];
#pragma unroll
        for (int j = 0; j < 32; ++j) qv[j] = (phQ & 1) ? sQ[j + 1] : sQ[j];
#pragma unroll
        for (int gg = 0; gg < 4; ++gg) {
            u16x8 qw;
#pragma unroll
            for (int j = 0; j < 8; ++j)
                qw[j] = f2bf_rne(__logf(qv[gg * 8 + j]));
            *reinterpret_cast<u16x8*>(
                &lds[p][(BM + rowQ) * 64 + ((hq * 32 + gg * 8) ^ swQ)]) = qw;
        }
    };

    auto mfma_phase = [&](int p) {
#pragma unroll
        for (int half = 0; half < 2; ++half) {
            const int dd = half * 32;
            bf16x8 af[2], qf[4];
#pragma unroll
            for (int mt = 0; mt < 2; ++mt) {
                const int r = wm + mt * 16 + lrow;
                const int c = (dd + kg * 8) ^ ((r & 7) << 3);
                af[mt] = *reinterpret_cast<const bf16x8*>(&lds[p][r * 64 + c]);
            }
#pragma unroll
            for (int nt = 0; nt < 4; ++nt) {
                const int r = wn + nt * 16 + lrow;
                const int c = (dd + kg * 8) ^ ((r & 7) << 3);
                qf[nt] = *reinterpret_cast<const bf16x8*>(&lds[p][(BM + r) * 64 + c]);
            }
#pragma unroll
            for (int mt = 0; mt < 2; ++mt)
#pragma unroll
                for (int nt = 0; nt < 4; ++nt)
                    acc[mt][nt] = __builtin_amdgcn_mfma_f32_16x16x32_bf16(
                        af[mt], qf[nt], acc[mt][nt], 0, 0, 0);
        }
    };

    if (d0 < dend) {
        load_step(d0);
        convert_write(0);
        __syncthreads();
        int p = 0;
        for (int dt = d0; dt < dend; dt += BK) {
            const int nxt = dt + BK;
            const bool more = nxt < dend;          // uniform across block
            if (more) load_step(nxt);              // issue a full step early
            mfma_phase(p);                         // compute current buffer
            if (more) {
                convert_write(p ^ 1);              // vmcnt wait lands here
                __syncthreads();                   // one barrier per step
                p ^= 1;
            }
        }
    }

    // ---- epilogue (C/D: col=lane&15 -> b, row=(lane>>4)*4+i -> k) ----
#pragma unroll
    for (int mt = 0; mt < 2; ++mt)
#pragma unroll
        for (int nt = 0; nt < 4; ++nt) {
            const int kk = k0 + wm + mt * 16 + kg * 4;
            const int bb = wn + nt * 16 + lrow;
            if (WSP) {
                *reinterpret_cast<f32x4*>(&outc[((size_t)z * B + bb) * K + kk]) = acc[mt][nt];
            } else {
                float* dst = &outc[(size_t)bb * K + kk];
#pragma unroll
                for (int i = 0; i < 4; ++i) atomicAdd(&dst[i], acc[mt][nt][i]);
            }
        }

    // ---- self partials: reduce 8 threads per A row, deterministic store ----
    float s = selfacc;
    s += __shfl_xor(s, 1);
    s += __shfl_xor(s, 2);
    s += __shfl_xor(s, 4);
    if (tq8 == 0) selfp[(size_t)z * K + ar] = s;
}

// ---------------- reduce self partials ----------------
__global__ __launch_bounds__(256)
void selfsum_kernel(const float* __restrict__ selfp, float* __restrict__ selftot, int sch)
{
    const int k = blockIdx.x * 256 + threadIdx.x;
    float s = 0.f;
    for (int z = 0; z < sch; ++z) s += selfp[(size_t)z * K + k];
    selftot[k] = s;
}

// ---------------- per-query top-NC candidates + rescore-need gap flag ----------
template<bool WSP>
__global__ __launch_bounds__(256)
void topk_kernel(const float* __restrict__ outc, const float* __restrict__ selftot,
                 int* __restrict__ cand, int* __restrict__ need, int sch)
{
    const int b = blockIdx.x, t = threadIdx.x;
    float v[8];
#pragma unroll
    for (int i = 0; i < 8; ++i) {
        const int k = i * 256 + t;
        float cv = 0.f;
        if (WSP) {
            for (int z = 0; z < sch; ++z) cv += outc[((size_t)z * B + b) * K + k];
        } else {
            cv = outc[(size_t)b * K + k];
        }
        v[i] = selftot[k] - cv;
    }
    __shared__ float sv[256];
    __shared__ int   si[256];
    __shared__ float topv[2];
    for (int r = 0; r < NC; ++r) {
        float bv = 3.4e38f; int bk = K;
#pragma unroll
        for (int i = 0; i < 8; ++i) {
            const int k = i * 256 + t;
            if (v[i] < bv) { bv = v[i]; bk = k; }
        }
        sv[t] = bv; si[t] = bk;
        __syncthreads();
        for (int off = 128; off > 0; off >>= 1) {
            if (t < off) {
                if (sv[t + off] < sv[t] || (sv[t + off] == sv[t] && si[t + off] < si[t])) {
                    sv[t] = sv[t + off]; si[t] = si[t + off];
                }
            }
            __syncthreads();
        }
        const int kwin = si[0];
        if ((kwin & 255) == t) v[kwin >> 8] = 3.4e38f;
        if (t == 0) {
            cand[b * NC + r] = kwin;
            if (r < 2) topv[r] = sv[0];
        }
        __syncthreads();
    }
    if (t == 0) need[b] = (topv[1] - topv[0] < MARGIN) ? 1 : 0;
}

// ---------------- exact fp64 rescore of flagged queries (D split in halves) ----
__global__ __launch_bounds__(512)
void rescore_kernel(const float* __restrict__ query, const float* __restrict__ anchor,
                    const int* __restrict__ cand, const int* __restrict__ need,
                    double* __restrict__ pp)
{
    const int b = blockIdx.x, h = blockIdx.y, t = threadIdx.x;
    if (!need[b]) return;   // uniform exit before any barrier
    const int dlo = h * 25129;
    const int dhi = min(D, dlo + 25129);
    int ks[NC];
#pragma unroll
    for (int c = 0; c < NC; ++c) ks[c] = cand[b * NC + c];
    const float* qrow = query + (size_t)b * D;

    double a8[NC];
#pragma unroll
    for (int c = 0; c < NC; ++c) a8[c] = 0.0;

    for (int d = dlo + t; d < dhi; d += 512) {
        const double lqv = (double)logf(qrow[d]);
#pragma unroll
        for (int c = 0; c < NC; ++c)
            a8[c] = fma((double)anchor[(size_t)ks[c] * D + d], lqv, a8[c]);
    }

    __shared__ double red[512];
    for (int c = 0; c < NC; ++c) {
        red[t] = a8[c];
        __syncthreads();
        for (int off = 256; off > 0; off >>= 1) {
            if (t < off) red[t] += red[t + off];
            __syncthreads();
        }
        if (t == 0) pp[((size_t)b * 2 + h) * NC + c] = red[0];
        __syncthreads();
    }
}

// ---------------- final decision + label gather ----------------
__global__ __launch_bounds__(256)
void final_kernel(const double* __restrict__ pp, const float* __restrict__ selftot,
                  const int* __restrict__ cand, const int* __restrict__ need,
                  const int* __restrict__ label, int* __restrict__ out)
{
    const int b = threadIdx.x;
    if (!need[b]) { out[b] = label[cand[b * NC]]; return; }
    float best = 3.4e38f; int bk = K;
#pragma unroll
    for (int c = 0; c < NC; ++c) {
        const int k = cand[b * NC + c];
        const double cv = pp[((size_t)b * 2 + 0) * NC + c] + pp[((size_t)b * 2 + 1) * NC + c];
        const float sc = selftot[k] - (float)cv;
        if (sc < best || (sc == best && k < bk)) { best = sc; bk = k; }
    }
    out[b] = label[bk];
}

extern "C" void kernel_launch(void* const* d_in, const int* in_sizes, int n_in,
                              void* d_out, int out_size, void* d_ws, size_t ws_size,
                              hipStream_t stream)
{
    const float* query  = (const float*)d_in[0];   // [B*D]
    const float* anchor = (const float*)d_in[1];   // [K*D]
    const int*   label  = (const int*)d_in[2];     // [K]
    int* out = (int*)d_out;

    size_t cur = 0;
    auto alloc = [&](size_t bytes) -> void* {
        cur = (cur + 255) & ~(size_t)255;
        void* p = (char*)d_ws + cur;
        cur += bytes;
        return p;
    };

    // small fixed pool (~190 KB)
    float*  selfp   = (float*)alloc((size_t)16 * K * 4);
    float*  selftot = (float*)alloc((size_t)K * 4);
    int*    cand    = (int*)alloc((size_t)B * NC * 4);
    int*    need    = (int*)alloc((size_t)B * 4);
    double* pp      = (double*)alloc((size_t)B * 2 * NC * 8);
    const size_t fixed_end = cur;

    // largest chunk count whose deterministic partials fit the remaining ws
    int sch = 0;
    const int ladder[4] = {12, 8, 4, 2};
    for (int i = 0; i < 4; ++i) {
        const int s = ladder[i];
        if (fixed_end + (size_t)s * B * K * 4 + 256 <= ws_size) { sch = s; break; }
    }

    if (sch) {
        // ---- deterministic-partials path ----
        float* part = (float*)alloc((size_t)sch * B * K * 4);
        const int dc = (((D + sch - 1) / sch) + BK - 1) & ~(BK - 1);
        gemm_kernel<true><<<32 * sch, 512, 0, stream>>>(anchor, query, part, selfp, dc, sch);
        selfsum_kernel<<<K / 256, 256, 0, stream>>>(selfp, selftot, sch);
        topk_kernel<true><<<B, 256, 0, stream>>>(part, selftot, cand, need, sch);
    } else {
        // ---- atomic fallback (tiny ws) ----
        float* cross = (float*)alloc((size_t)B * K * 4);
        const int s8 = 8;
        const int dc = (((D + s8 - 1) / s8) + BK - 1) & ~(BK - 1);
        hipMemsetAsync(cross, 0, (size_t)B * K * sizeof(float), stream);
        gemm_kernel<false><<<32 * s8, 512, 0, stream>>>(anchor, query, cross, selfp, dc, s8);
        selfsum_kernel<<<K / 256, 256, 0, stream>>>(selfp, selftot, s8);
        topk_kernel<false><<<B, 256, 0, stream>>>(cross, selftot, cand, need, s8);
    }

    rescore_kernel<<<dim3(B, 2), 512, 0, stream>>>(query, anchor, cand, need, pp);
    final_kernel<<<1, 256, 0, stream>>>(pp, selftot, cand, need, label, out);
}

// Round 6
// 2086.757 us; speedup vs baseline: 1.0028x; 1.0028x over previous
//
#include <hip/hip_runtime.h>

// AnchorStore: KL-argmin 1-NN.
//   score[b,k] = sum_d A[k,d]*log A[k,d]  -  sum_d A[k,d]*log Q[b,d]
//   out[b] = label[argmin_k score[b,k]],  K=2048, D=50257, B=256.
// bf16 MFMA GEMM (approx cross) with deterministic per-D-chunk partials in ws,
// on-the-fly log(Q) (no lq buffer so partials fit the ~29MB workspace),
// single-buffer 40KB LDS + reg prefetch (round-4 structure, 0 bank conflicts),
// exact fp32 self-term, gap-gated fp64 top-8 rescore, label gather.
// NOTE: __launch_bounds__ 2nd arg behaves as min BLOCKS/CU here (round-5
// post-mortem: (512,4) forced VGPR=64 -> 4.5GB scratch spills). Use (512,2).

constexpr int K   = 2048;
constexpr int D   = 50257;
constexpr int B   = 256;
constexpr int BM  = 64;
constexpr int BK  = 64;
constexpr int NC  = 8;
constexpr float MARGIN = 4.0f;   // approx-score gap below which we rescore

typedef __attribute__((ext_vector_type(8))) short bf16x8;
typedef __attribute__((ext_vector_type(4))) float f32x4;
typedef __attribute__((ext_vector_type(8))) unsigned short u16x8;

__device__ inline unsigned short f2bf_rne(float f) {
    union { float f; unsigned u; } v; v.f = f;
    unsigned r = v.u + 0x7FFFu + ((v.u >> 16) & 1u);
    return (unsigned short)(r >> 16);
}

// ---------------- main GEMM: cross[b][k] partials over D-chunks ----------------
// WSP: deterministic part[z][B][K] stores; else atomicAdd into cross[B][K].
template<bool WSP>
__global__ __launch_bounds__(512, 2)
void gemm_kernel(const float* __restrict__ anchor,
                 const float* __restrict__ query,
                 float* __restrict__ outc,
                 float* __restrict__ selfp,   // [sch][K]
                 int dc, int sch)
{
    // XCD-grouped swizzle: consecutive g on one XCD; the 32 x-blocks of a z
    // run on the same XCD so the Q slice stays L2-resident.
    const int nb8 = gridDim.x >> 3;                      // blocks per XCD
    const int g   = (blockIdx.x & 7) * nb8 + (blockIdx.x >> 3);
    const int z   = g >> 5;
    const int x   = g & 31;

    const int t    = threadIdx.x;
    const int k0   = x * BM;
    const int d0   = z * dc;
    const int dend = min(d0 + dc, D);

    // single-buffer LDS: A rows [0,64), Q rows [64,320), 64 ushorts/row = 40KB
    __shared__ __align__(16) unsigned short lds[(BM + B) * 64];

    // A staging: row = t>>3 (0..63), 8 cols at (t&7)*8
    const int rowA = t >> 3;
    const int tq8  = t & 7;
    const int ar   = k0 + rowA;
    const int swA  = (rowA & 7) << 3;
    const float* Arow = anchor + (size_t)ar * D;

    // Q staging: row = t>>1 (0..255), 32 cols at (t&1)*32
    const int rowQ = t >> 1;
    const int hq   = t & 1;
    const int swQ  = (rowQ & 7) << 3;
    const float* Qrow = query + (size_t)rowQ * D;

    // MFMA geometry: 8 waves in 2(m) x 4(n); wave tile 32x64
    const int w    = t >> 6;
    const int lane = t & 63;
    const int wm   = (w >> 2) * 32;
    const int wn   = (w & 3) * 64;
    const int lrow = lane & 15;
    const int kg   = lane >> 4;

    f32x4 acc[2][4];
#pragma unroll
    for (int mt = 0; mt < 2; ++mt)
#pragma unroll
        for (int nt = 0; nt < 4; ++nt)
#pragma unroll
            for (int i = 0; i < 4; ++i) acc[mt][nt][i] = 0.f;

    float selfacc = 0.f;

    float wfA[12]; int phA = 0;
    float wfQ[36]; int phQ = 0;

    auto load_step = [&](int dt) {
        // ---- A: 8 wanted cols; 3 aligned float4 cover [g0-ph, g0-ph+12) ----
        const int dbase = dt + tq8 * 8;
        if (dbase + 12 <= dend) {
            const size_t g0 = (size_t)ar * D + dbase;
            phA = (int)(g0 & 3);
            const float4* wp = reinterpret_cast<const float4*>(anchor + (g0 - phA));
            const float4 w0 = wp[0], w1 = wp[1], w2 = wp[2];
            wfA[0] = w0.x; wfA[1]  = w0.y; wfA[2]  = w0.z; wfA[3]  = w0.w;
            wfA[4] = w1.x; wfA[5]  = w1.y; wfA[6]  = w1.z; wfA[7]  = w1.w;
            wfA[8] = w2.x; wfA[9]  = w2.y; wfA[10] = w2.z; wfA[11] = w2.w;
        } else {
            phA = 0;
#pragma unroll
            for (int j = 0; j < 8; ++j) {
                const int d = dbase + j;
                wfA[j] = (d < dend) ? Arow[d] : 0.f;
            }
#pragma unroll
            for (int j = 8; j < 12; ++j) wfA[j] = 0.f;
        }
        // ---- Q: 32 wanted cols; 9 aligned float4 cover [g0-ph, g0-ph+36) ----
        const int qb = dt + hq * 32;
        if (qb + 36 <= dend) {
            const size_t g0 = (size_t)rowQ * D + qb;
            phQ = (int)(g0 & 3);
            const float4* wp = reinterpret_cast<const float4*>(query + (g0 - phQ));
#pragma unroll
            for (int gg = 0; gg < 9; ++gg) {
                const float4 v = wp[gg];
                wfQ[gg * 4 + 0] = v.x; wfQ[gg * 4 + 1] = v.y;
                wfQ[gg * 4 + 2] = v.z; wfQ[gg * 4 + 3] = v.w;
            }
        } else {
            phQ = 0;
#pragma unroll
            for (int j = 0; j < 32; ++j) {
                const int d = qb + j;
                wfQ[j] = (d < dend) ? Qrow[d] : 1.f;   // log(1)=0
            }
#pragma unroll
            for (int j = 32; j < 36; ++j) wfQ[j] = 1.f;
        }
    };

    auto convert_write = [&]() {
        // ---- A: phase-select 8, fused exact self-term, bf16, store ----
        float sA[9], av[8];
#pragma unroll
        for (int j = 0; j < 9; ++j) sA[j] = (phA & 2) ? wfA[j + 2] : wfA[j];
#pragma unroll
        for (int j = 0; j < 8; ++j) av[j] = (phA & 1) ? sA[j + 1] : sA[j];
        unsigned short abf[8];
#pragma unroll
        for (int j = 0; j < 8; ++j) {
            if (av[j] > 0.f) selfacc = fmaf(av[j], __logf(av[j]), selfacc);
            abf[j] = f2bf_rne(av[j]);
        }
        unsigned short* a0 = &lds[rowA * 64 + ((tq8 * 8) ^ swA)];
        reinterpret_cast<ushort4*>(a0)[0] = ushort4{abf[0], abf[1], abf[2], abf[3]};
        reinterpret_cast<ushort4*>(a0)[1] = ushort4{abf[4], abf[5], abf[6], abf[7]};
        // ---- Q: phase-select 32, log, bf16, store ----
        float sQ[34], qv[32];
#pragma unroll
        for (int j = 0; j < 34; ++j) sQ[j] = (phQ & 2) ? wfQ[j + 2] : wfQ[j];
#pragma unroll
        for (int j = 0; j < 32; ++j) qv[j] = (phQ & 1) ? sQ[j + 1] : sQ[j];
#pragma unroll
        for (int gg = 0; gg < 4; ++gg) {
            u16x8 qw;
#pragma unroll
            for (int j = 0; j < 8; ++j)
                qw[j] = f2bf_rne(__logf(qv[gg * 8 + j]));
            *reinterpret_cast<u16x8*>(
                &lds[(BM + rowQ) * 64 + ((hq * 32 + gg * 8) ^ swQ)]) = qw;
        }
    };

    auto mfma_phase = [&]() {
#pragma unroll
        for (int half = 0; half < 2; ++half) {
            const int dd = half * 32;
            bf16x8 af[2], qf[4];
#pragma unroll
            for (int mt = 0; mt < 2; ++mt) {
                const int r = wm + mt * 16 + lrow;
                const int c = (dd + kg * 8) ^ ((r & 7) << 3);
                af[mt] = *reinterpret_cast<const bf16x8*>(&lds[r * 64 + c]);
            }
#pragma unroll
            for (int nt = 0; nt < 4; ++nt) {
                const int r = wn + nt * 16 + lrow;
                const int c = (dd + kg * 8) ^ ((r & 7) << 3);
                qf[nt] = *reinterpret_cast<const bf16x8*>(&lds[(BM + r) * 64 + c]);
            }
#pragma unroll
            for (int mt = 0; mt < 2; ++mt)
#pragma unroll
                for (int nt = 0; nt < 4; ++nt)
                    acc[mt][nt] = __builtin_amdgcn_mfma_f32_16x16x32_bf16(
                        af[mt], qf[nt], acc[mt][nt], 0, 0, 0);
        }
    };

    if (d0 < dend) {
        load_step(d0);
        for (int dt = d0; dt < dend; dt += BK) {
            convert_write();                       // vmcnt wait for step-dt data
            __syncthreads();                       // writes visible to all waves
            if (dt + BK < dend) load_step(dt + BK); // next loads fly during MFMA
            mfma_phase();
            __syncthreads();                       // readers done before next write
        }
    }

    // ---- epilogue (C/D: col=lane&15 -> b, row=(lane>>4)*4+i -> k) ----
#pragma unroll
    for (int mt = 0; mt < 2; ++mt)
#pragma unroll
        for (int nt = 0; nt < 4; ++nt) {
            const int kk = k0 + wm + mt * 16 + kg * 4;
            const int bb = wn + nt * 16 + lrow;
            if (WSP) {
                *reinterpret_cast<f32x4*>(&outc[((size_t)z * B + bb) * K + kk]) = acc[mt][nt];
            } else {
                float* dst = &outc[(size_t)bb * K + kk];
#pragma unroll
                for (int i = 0; i < 4; ++i) atomicAdd(&dst[i], acc[mt][nt][i]);
            }
        }

    // ---- self partials: reduce 8 threads per A row, deterministic store ----
    float s = selfacc;
    s += __shfl_xor(s, 1);
    s += __shfl_xor(s, 2);
    s += __shfl_xor(s, 4);
    if (tq8 == 0) selfp[(size_t)z * K + ar] = s;
}

// ---------------- reduce self partials ----------------
__global__ __launch_bounds__(256)
void selfsum_kernel(const float* __restrict__ selfp, float* __restrict__ selftot, int sch)
{
    const int k = blockIdx.x * 256 + threadIdx.x;
    float s = 0.f;
    for (int z = 0; z < sch; ++z) s += selfp[(size_t)z * K + k];
    selftot[k] = s;
}

// ---------------- per-query top-NC candidates + rescore-need gap flag ----------
template<bool WSP>
__global__ __launch_bounds__(256)
void topk_kernel(const float* __restrict__ outc, const float* __restrict__ selftot,
                 int* __restrict__ cand, int* __restrict__ need, int sch)
{
    const int b = blockIdx.x, t = threadIdx.x;
    float v[8];
#pragma unroll
    for (int i = 0; i < 8; ++i) {
        const int k = i * 256 + t;
        float cv = 0.f;
        if (WSP) {
            for (int z = 0; z < sch; ++z) cv += outc[((size_t)z * B + b) * K + k];
        } else {
            cv = outc[(size_t)b * K + k];
        }
        v[i] = selftot[k] - cv;
    }
    __shared__ float sv[256];
    __shared__ int   si[256];
    __shared__ float topv[2];
    for (int r = 0; r < NC; ++r) {
        float bv = 3.4e38f; int bk = K;
#pragma unroll
        for (int i = 0; i < 8; ++i) {
            const int k = i * 256 + t;
            if (v[i] < bv) { bv = v[i]; bk = k; }
        }
        sv[t] = bv; si[t] = bk;
        __syncthreads();
        for (int off = 128; off > 0; off >>= 1) {
            if (t < off) {
                if (sv[t + off] < sv[t] || (sv[t + off] == sv[t] && si[t + off] < si[t])) {
                    sv[t] = sv[t + off]; si[t] = si[t + off];
                }
            }
            __syncthreads();
        }
        const int kwin = si[0];
        if ((kwin & 255) == t) v[kwin >> 8] = 3.4e38f;
        if (t == 0) {
            cand[b * NC + r] = kwin;
            if (r < 2) topv[r] = sv[0];
        }
        __syncthreads();
    }
    if (t == 0) need[b] = (topv[1] - topv[0] < MARGIN) ? 1 : 0;
}

// ---------------- exact fp64 rescore of flagged queries (D split in halves) ----
__global__ __launch_bounds__(512)
void rescore_kernel(const float* __restrict__ query, const float* __restrict__ anchor,
                    const int* __restrict__ cand, const int* __restrict__ need,
                    double* __restrict__ pp)
{
    const int b = blockIdx.x, h = blockIdx.y, t = threadIdx.x;
    if (!need[b]) return;   // uniform exit before any barrier
    const int dlo = h * 25129;
    const int dhi = min(D, dlo + 25129);
    int ks[NC];
#pragma unroll
    for (int c = 0; c < NC; ++c) ks[c] = cand[b * NC + c];
    const float* qrow = query + (size_t)b * D;

    double a8[NC];
#pragma unroll
    for (int c = 0; c < NC; ++c) a8[c] = 0.0;

    for (int d = dlo + t; d < dhi; d += 512) {
        const double lqv = (double)logf(qrow[d]);
#pragma unroll
        for (int c = 0; c < NC; ++c)
            a8[c] = fma((double)anchor[(size_t)ks[c] * D + d], lqv, a8[c]);
    }

    __shared__ double red[512];
    for (int c = 0; c < NC; ++c) {
        red[t] = a8[c];
        __syncthreads();
        for (int off = 256; off > 0; off >>= 1) {
            if (t < off) red[t] += red[t + off];
            __syncthreads();
        }
        if (t == 0) pp[((size_t)b * 2 + h) * NC + c] = red[0];
        __syncthreads();
    }
}

// ---------------- final decision + label gather ----------------
__global__ __launch_bounds__(256)
void final_kernel(const double* __restrict__ pp, const float* __restrict__ selftot,
                  const int* __restrict__ cand, const int* __restrict__ need,
                  const int* __restrict__ label, int* __restrict__ out)
{
    const int b = threadIdx.x;
    if (!need[b]) { out[b] = label[cand[b * NC]]; return; }
    float best = 3.4e38f; int bk = K;
#pragma unroll
    for (int c = 0; c < NC; ++c) {
        const int k = cand[b * NC + c];
        const double cv = pp[((size_t)b * 2 + 0) * NC + c] + pp[((size_t)b * 2 + 1) * NC + c];
        const float sc = selftot[k] - (float)cv;
        if (sc < best || (sc == best && k < bk)) { best = sc; bk = k; }
    }
    out[b] = label[bk];
}

extern "C" void kernel_launch(void* const* d_in, const int* in_sizes, int n_in,
                              void* d_out, int out_size, void* d_ws, size_t ws_size,
                              hipStream_t stream)
{
    const float* query  = (const float*)d_in[0];   // [B*D]
    const float* anchor = (const float*)d_in[1];   // [K*D]
    const int*   label  = (const int*)d_in[2];     // [K]
    int* out = (int*)d_out;

    size_t cur = 0;
    auto alloc = [&](size_t bytes) -> void* {
        cur = (cur + 255) & ~(size_t)255;
        void* p = (char*)d_ws + cur;
        cur += bytes;
        return p;
    };

    // small fixed pool (~190 KB)
    float*  selfp   = (float*)alloc((size_t)16 * K * 4);
    float*  selftot = (float*)alloc((size_t)K * 4);
    int*    cand    = (int*)alloc((size_t)B * NC * 4);
    int*    need    = (int*)alloc((size_t)B * 4);
    double* pp      = (double*)alloc((size_t)B * 2 * NC * 8);
    const size_t fixed_end = cur;

    // largest chunk count whose deterministic partials fit the remaining ws
    int sch = 0;
    const int ladder[4] = {12, 8, 4, 2};
    for (int i = 0; i < 4; ++i) {
        const int s = ladder[i];
        if (fixed_end + (size_t)s * B * K * 4 + 256 <= ws_size) { sch = s; break; }
    }

    if (sch) {
        // ---- deterministic-partials path ----
        float* part = (float*)alloc((size_t)sch * B * K * 4);
        const int dc = (((D + sch - 1) / sch) + BK - 1) & ~(BK - 1);
        gemm_kernel<true><<<32 * sch, 512, 0, stream>>>(anchor, query, part, selfp, dc, sch);
        selfsum_kernel<<<K / 256, 256, 0, stream>>>(selfp, selftot, sch);
        topk_kernel<true><<<B, 256, 0, stream>>>(part, selftot, cand, need, sch);
    } else {
        // ---- atomic fallback (tiny ws) ----
        float* cross = (float*)alloc((size_t)B * K * 4);
        const int s8 = 8;
        const int dc = (((D + s8 - 1) / s8) + BK - 1) & ~(BK - 1);
        hipMemsetAsync(cross, 0, (size_t)B * K * sizeof(float), stream);
        gemm_kernel<false><<<32 * s8, 512, 0, stream>>>(anchor, query, cross, selfp, dc, s8);
        selfsum_kernel<<<K / 256, 256, 0, stream>>>(selfp, selftot, s8);
        topk_kernel<false><<<B, 256, 0, stream>>>(cross, selftot, cand, need, s8);
    }

    rescore_kernel<<<dim3(B, 2), 512, 0, stream>>>(query, anchor, cand, need, pp);
    final_kernel<<<1, 256, 0, stream>>>(pp, selftot, cand, need, label, out);
}

// Round 7
// 630.030 us; speedup vs baseline: 3.3213x; 3.3122x over previous
//
#include <hip/hip_runtime.h>

// AnchorStore: KL-argmin 1-NN.
//   score[b,k] = sum_d A[k,d]*log A[k,d]  -  sum_d A[k,d]*log Q[b,d]
//   out[b] = label[argmin_k score[b,k]],  K=2048, D=50257, B=256.
//
// Two-phase D-split (ws in [28.04,30.14) MB, measured rounds 3-6):
//   phase p: lq_kernel writes bf16 log(Q) slice (13.0MB, zero-padded);
//            gemm writes 6 deterministic fp32 partials [z][B][K] (12.6MB);
//   phase 0 result reduced into crossA (2.1MB) before phase 1 reuses buffers.
// Peak ws = 27.84MB. No atomics, no on-the-fly log (r5/6: scratch spills +
// 32x-redundant transcendentals). GEMM uses round-4's proven lean register
// shape: lq as u16x8[4], A via 2xfloat4 cover + 2-stage phase select.

constexpr int K    = 2048;
constexpr int D    = 50257;
constexpr int B    = 256;
constexpr int BM   = 32;
constexpr int BK   = 64;
constexpr int DSPL = 25344;          // phase split (mult of 64)
constexpr int LQS  = 25408;          // lq row stride (mult of 64, >= DLr both phases)
constexpr int NC   = 8;
constexpr float MARGIN = 4.0f;

typedef __attribute__((ext_vector_type(8))) short bf16x8;
typedef __attribute__((ext_vector_type(4))) float f32x4;
typedef __attribute__((ext_vector_type(8))) unsigned short u16x8;

__device__ inline unsigned short f2bf_rne(float f) {
    union { float f; unsigned u; } v; v.f = f;
    unsigned r = v.u + 0x7FFFu + ((v.u >> 16) & 1u);
    return (unsigned short)(r >> 16);
}

// ---- lq[b][c] = bf16(log(Q[b][aoff+c])) for c<DL, 0 for c in [DL,LQS) ----
__global__ __launch_bounds__(256)
void lq_kernel(const float* __restrict__ q, unsigned short* __restrict__ lq,
               int aoff, int DL)
{
    const int stride = gridDim.x * blockDim.x;
    const int total  = B * (LQS / 8);
    for (int c = blockIdx.x * blockDim.x + threadIdx.x; c < total; c += stride) {
        const int b  = c / (LQS / 8);
        const int o8 = (c % (LQS / 8)) * 8;
        u16x8 w;
#pragma unroll
        for (int j = 0; j < 8; ++j) {
            const int d = o8 + j;
            const float v = (d < DL) ? q[(size_t)b * D + aoff + d] : 1.f; // log(1)=0
            w[j] = f2bf_rne(__logf(v));
        }
        *reinterpret_cast<u16x8*>(&lq[(size_t)b * LQS + o8]) = w;
    }
}

// ---- GEMM: part[z][B][K] (z local to phase), selfp[zoff+z][K] ----
__global__ __launch_bounds__(512, 2)
void gemm_kernel(const float* __restrict__ anchor,
                 const unsigned short* __restrict__ lq,
                 float* __restrict__ part,     // [pch][B][K]
                 float* __restrict__ selfp,    // [2*pch][K]
                 int dc, int DL, int aoff, int zoff)
{
    // XCD-grouped swizzle: XCD i gets contiguous g-range -> one z's lq slice
    // (2.2MB) stays L2-resident per XCD.
    const int nb8 = gridDim.x >> 3;
    const int g   = (blockIdx.x & 7) * nb8 + (blockIdx.x >> 3);
    const int z   = g >> 6;
    const int x   = g & 63;

    const int t    = threadIdx.x;
    const int k0   = x * BM;
    const int d0   = z * dc;
    const int DLr  = (DL + 63) & ~63;
    const int dend = min(d0 + dc, DLr);

    // LDS: A rows [0,32), Q rows [32,288), 64 ushorts/row = 36KB
    __shared__ __align__(16) unsigned short lds[(BM + B) * 64];

    // A staging: row = t>>4 (0..31), 4 cols at (t&15)*4
    const int rowA = t >> 4;
    const int cA   = (t & 15) * 4;
    const int ar   = k0 + rowA;
    const int swA  = (rowA & 7) << 3;
    const float* Arow = anchor + (size_t)ar * D + aoff;

    // Q staging: row = t>>1 (0..255), 32 cols at (t&1)*32
    const int rowQ = t >> 1;
    const int hq   = (t & 1) * 32;
    const int swQ  = (rowQ & 7) << 3;
    const unsigned short* LQrow = lq + (size_t)rowQ * LQS;

    // MFMA: 8 waves, 1(m) x 8(n); wave tile 32x32
    const int w    = t >> 6;
    const int lane = t & 63;
    const int wn   = w * 32;
    const int lrow = lane & 15;
    const int kg   = lane >> 4;

    f32x4 acc[2][2];
#pragma unroll
    for (int mt = 0; mt < 2; ++mt)
#pragma unroll
        for (int nt = 0; nt < 2; ++nt)
#pragma unroll
            for (int i = 0; i < 4; ++i) acc[mt][nt][i] = 0.f;

    float selfacc = 0.f;

    float wf[8]; int ph = 0;
    u16x8 qreg[4];

    auto load_step = [&](int dt) {
        // A: 4 wanted cols; 2 aligned float4 cover [g0-ph, g0-ph+8)
        const int dbase = dt + cA;
        if (dbase + 8 <= DL) {
            const size_t g0 = (size_t)ar * D + aoff + dbase;
            ph = (int)(g0 & 3);
            const float4* wp = reinterpret_cast<const float4*>(anchor + (g0 - ph));
            const float4 w0 = wp[0], w1 = wp[1];
            wf[0] = w0.x; wf[1] = w0.y; wf[2] = w0.z; wf[3] = w0.w;
            wf[4] = w1.x; wf[5] = w1.y; wf[6] = w1.z; wf[7] = w1.w;
        } else {
            ph = 0;
#pragma unroll
            for (int j = 0; j < 4; ++j) {
                const int d = dbase + j;
                wf[j] = (d < DL) ? Arow[d] : 0.f;
            }
#pragma unroll
            for (int j = 4; j < 8; ++j) wf[j] = 0.f;
        }
        // Q: 4 x u16x8 from lq (pre-logged bf16; rows padded with zeros)
        const int qb = dt + hq;
#pragma unroll
        for (int gg = 0; gg < 4; ++gg)
            qreg[gg] = *reinterpret_cast<const u16x8*>(&LQrow[qb + 8 * gg]);
    };

    auto convert_write = [&]() {
        // A: 2-stage phase select (compile-time indices), self-term, bf16
        float s5[5], av[4];
#pragma unroll
        for (int j = 0; j < 5; ++j) s5[j] = (ph & 2) ? wf[j + 2] : wf[j];
#pragma unroll
        for (int j = 0; j < 4; ++j) av[j] = (ph & 1) ? s5[j + 1] : s5[j];
        ushort4 abf;
        {
            float a0 = av[0], a1 = av[1], a2 = av[2], a3 = av[3];
            if (a0 > 0.f) selfacc = fmaf(a0, __logf(a0), selfacc);
            if (a1 > 0.f) selfacc = fmaf(a1, __logf(a1), selfacc);
            if (a2 > 0.f) selfacc = fmaf(a2, __logf(a2), selfacc);
            if (a3 > 0.f) selfacc = fmaf(a3, __logf(a3), selfacc);
            abf = ushort4{f2bf_rne(a0), f2bf_rne(a1), f2bf_rne(a2), f2bf_rne(a3)};
        }
        *reinterpret_cast<ushort4*>(&lds[rowA * 64 + (cA ^ swA)]) = abf;
#pragma unroll
        for (int gg = 0; gg < 4; ++gg)
            *reinterpret_cast<u16x8*>(&lds[(BM + rowQ) * 64 + ((hq + 8 * gg) ^ swQ)]) = qreg[gg];
    };

    auto mfma_phase = [&]() {
#pragma unroll
        for (int half = 0; half < 2; ++half) {
            const int dd = half * 32;
            bf16x8 af[2], qf[2];
#pragma unroll
            for (int mt = 0; mt < 2; ++mt) {
                const int r = mt * 16 + lrow;
                const int c = (dd + kg * 8) ^ ((r & 7) << 3);
                af[mt] = *reinterpret_cast<const bf16x8*>(&lds[r * 64 + c]);
            }
#pragma unroll
            for (int nt = 0; nt < 2; ++nt) {
                const int r = wn + nt * 16 + lrow;
                const int c = (dd + kg * 8) ^ ((r & 7) << 3);
                qf[nt] = *reinterpret_cast<const bf16x8*>(&lds[(BM + r) * 64 + c]);
            }
#pragma unroll
            for (int mt = 0; mt < 2; ++mt)
#pragma unroll
                for (int nt = 0; nt < 2; ++nt)
                    acc[mt][nt] = __builtin_amdgcn_mfma_f32_16x16x32_bf16(
                        af[mt], qf[nt], acc[mt][nt], 0, 0, 0);
        }
    };

    if (d0 < dend) {
        load_step(d0);
        for (int dt = d0; dt < dend; dt += BK) {
            convert_write();                        // waits on step-dt loads
            __syncthreads();                        // LDS visible
            if (dt + BK < dend) load_step(dt + BK); // next loads fly over MFMA
            mfma_phase();
            __syncthreads();                        // readers done
        }
    }

    // epilogue (C/D: col=lane&15 -> b, row=(lane>>4)*4+i -> k)
#pragma unroll
    for (int mt = 0; mt < 2; ++mt)
#pragma unroll
        for (int nt = 0; nt < 2; ++nt) {
            const int kk = k0 + mt * 16 + kg * 4;
            const int bb = wn + nt * 16 + lrow;
            *reinterpret_cast<f32x4*>(&part[((size_t)z * B + bb) * K + kk]) = acc[mt][nt];
        }

    // self partials: 16 staging threads per A row
    float s = selfacc;
    s += __shfl_xor(s, 1);
    s += __shfl_xor(s, 2);
    s += __shfl_xor(s, 4);
    s += __shfl_xor(s, 8);
    if ((t & 15) == 0) selfp[(size_t)(zoff + z) * K + ar] = s;
}

// ---- crossA[i] = sum_z part[z][i] (phase-0 reduction) ----
__global__ __launch_bounds__(256)
void reduce_kernel(const float* __restrict__ part, float* __restrict__ crossA, int pch)
{
    const int i = blockIdx.x * 256 + threadIdx.x;           // f32x4 index
    const f32x4* p4 = reinterpret_cast<const f32x4*>(part);
    f32x4 s = p4[i];
    for (int z = 1; z < pch; ++z) {
        const f32x4 v = p4[(size_t)z * (B * K / 4) + i];
#pragma unroll
        for (int j = 0; j < 4; ++j) s[j] += v[j];
    }
    reinterpret_cast<f32x4*>(crossA)[i] = s;
}

// ---- reduce self partials over 2*pch rows ----
__global__ __launch_bounds__(256)
void selfsum_kernel(const float* __restrict__ selfp, float* __restrict__ selftot, int rows)
{
    const int k = blockIdx.x * 256 + threadIdx.x;
    float s = 0.f;
    for (int z = 0; z < rows; ++z) s += selfp[(size_t)z * K + k];
    selftot[k] = s;
}

// ---- per-query top-NC + rescore-need gap flag ----
__global__ __launch_bounds__(256)
void topk_kernel(const float* __restrict__ crossA, const float* __restrict__ part,
                 const float* __restrict__ selftot,
                 int* __restrict__ cand, int* __restrict__ need, int pch)
{
    const int b = blockIdx.x, t = threadIdx.x;
    float v[8];
#pragma unroll
    for (int i = 0; i < 8; ++i) {
        const int k = i * 256 + t;
        float cv = crossA[(size_t)b * K + k];
        for (int z = 0; z < pch; ++z) cv += part[((size_t)z * B + b) * K + k];
        v[i] = selftot[k] - cv;
    }
    __shared__ float sv[256];
    __shared__ int   si[256];
    __shared__ float topv[2];
    for (int r = 0; r < NC; ++r) {
        float bv = 3.4e38f; int bk = K;
#pragma unroll
        for (int i = 0; i < 8; ++i) {
            const int k = i * 256 + t;
            if (v[i] < bv) { bv = v[i]; bk = k; }
        }
        sv[t] = bv; si[t] = bk;
        __syncthreads();
        for (int off = 128; off > 0; off >>= 1) {
            if (t < off) {
                if (sv[t + off] < sv[t] || (sv[t + off] == sv[t] && si[t + off] < si[t])) {
                    sv[t] = sv[t + off]; si[t] = si[t + off];
                }
            }
            __syncthreads();
        }
        const int kwin = si[0];
        if ((kwin & 255) == t) v[kwin >> 8] = 3.4e38f;
        if (t == 0) {
            cand[b * NC + r] = kwin;
            if (r < 2) topv[r] = sv[0];
        }
        __syncthreads();
    }
    if (t == 0) need[b] = (topv[1] - topv[0] < MARGIN) ? 1 : 0;
}

// ---- exact fp64 rescore of flagged queries (D split in halves) ----
__global__ __launch_bounds__(512)
void rescore_kernel(const float* __restrict__ query, const float* __restrict__ anchor,
                    const int* __restrict__ cand, const int* __restrict__ need,
                    double* __restrict__ pp)
{
    const int b = blockIdx.x, h = blockIdx.y, t = threadIdx.x;
    if (!need[b]) return;   // uniform exit before any barrier
    const int dlo = h * 25129;
    const int dhi = min(D, dlo + 25129);
    int ks[NC];
#pragma unroll
    for (int c = 0; c < NC; ++c) ks[c] = cand[b * NC + c];
    const float* qrow = query + (size_t)b * D;

    double a8[NC];
#pragma unroll
    for (int c = 0; c < NC; ++c) a8[c] = 0.0;

    for (int d = dlo + t; d < dhi; d += 512) {
        const double lqv = (double)logf(qrow[d]);
#pragma unroll
        for (int c = 0; c < NC; ++c)
            a8[c] = fma((double)anchor[(size_t)ks[c] * D + d], lqv, a8[c]);
    }

    __shared__ double red[512];
    for (int c = 0; c < NC; ++c) {
        red[t] = a8[c];
        __syncthreads();
        for (int off = 256; off > 0; off >>= 1) {
            if (t < off) red[t] += red[t + off];
            __syncthreads();
        }
        if (t == 0) pp[((size_t)b * 2 + h) * NC + c] = red[0];
        __syncthreads();
    }
}

// ---- final decision + label gather ----
__global__ __launch_bounds__(256)
void final_kernel(const double* __restrict__ pp, const float* __restrict__ selftot,
                  const int* __restrict__ cand, const int* __restrict__ need,
                  const int* __restrict__ label, int* __restrict__ out)
{
    const int b = threadIdx.x;
    if (!need[b]) { out[b] = label[cand[b * NC]]; return; }
    float best = 3.4e38f; int bk = K;
#pragma unroll
    for (int c = 0; c < NC; ++c) {
        const int k = cand[b * NC + c];
        const double cv = pp[((size_t)b * 2 + 0) * NC + c] + pp[((size_t)b * 2 + 1) * NC + c];
        const float sc = selftot[k] - (float)cv;
        if (sc < best || (sc == best && k < bk)) { best = sc; bk = k; }
    }
    out[b] = label[bk];
}

extern "C" void kernel_launch(void* const* d_in, const int* in_sizes, int n_in,
                              void* d_out, int out_size, void* d_ws, size_t ws_size,
                              hipStream_t stream)
{
    const float* query  = (const float*)d_in[0];   // [B*D]
    const float* anchor = (const float*)d_in[1];   // [K*D]
    const int*   label  = (const int*)d_in[2];     // [K]
    int* out = (int*)d_out;

    size_t cur = 0;
    auto alloc = [&](size_t bytes) -> void* {
        cur = (cur + 255) & ~(size_t)255;
        void* p = (char*)d_ws + cur;
        cur += bytes;
        return p;
    };

    unsigned short* lq      = (unsigned short*)alloc((size_t)B * LQS * 2); // 13.0MB
    float*          crossA  = (float*)alloc((size_t)B * K * 4);            //  2.1MB
    float*          selfp   = (float*)alloc((size_t)12 * K * 4);
    float*          selftot = (float*)alloc((size_t)K * 4);
    int*            cand    = (int*)alloc((size_t)B * NC * 4);
    int*            need    = (int*)alloc((size_t)B * 4);
    double*         pp      = (double*)alloc((size_t)B * 2 * NC * 8);
    const size_t fixed_end  = cur;

    // partials ladder: largest pch in [1,6] that fits
    int pch = 1;
    for (int s = 6; s >= 1; --s) {
        if (fixed_end + (size_t)s * B * K * 4 + 256 <= ws_size) { pch = s; break; }
    }
    float* part = (float*)alloc((size_t)pch * B * K * 4);                  // 12.6MB @6

    const int DL1 = DSPL, DL2 = D - DSPL;            // 25344, 24913
    const int dc1 = ((DL1 + pch - 1) / pch + 63) & ~63;
    const int dc2 = ((DL2 + pch - 1) / pch + 63) & ~63;

    // ---- phase 0: cols [0, DL1) ----
    lq_kernel<<<2048, 256, 0, stream>>>(query, lq, 0, DL1);
    gemm_kernel<<<64 * pch, 512, 0, stream>>>(anchor, lq, part, selfp, dc1, DL1, 0, 0);
    reduce_kernel<<<B * K / 4 / 256, 256, 0, stream>>>(part, crossA, pch);

    // ---- phase 1: cols [DL1, D) ----
    lq_kernel<<<2048, 256, 0, stream>>>(query, lq, DSPL, DL2);
    gemm_kernel<<<64 * pch, 512, 0, stream>>>(anchor, lq, part, selfp, dc2, DL2, DSPL, pch);

    selfsum_kernel<<<K / 256, 256, 0, stream>>>(selfp, selftot, 2 * pch);
    topk_kernel<<<B, 256, 0, stream>>>(crossA, part, selftot, cand, need, pch);
    rescore_kernel<<<dim3(B, 2), 512, 0, stream>>>(query, anchor, cand, need, pp);
    final_kernel<<<1, 256, 0, stream>>>(pp, selftot, cand, need, label, out);
}